// Round 5
// baseline (3326.860 us; speedup 1.0000x reference)
//
#include <hip/hip_runtime.h>
#include <math.h>

#define B   1024
#define IN  1024
#define HID 1024
#define OUT 512
#define T   100

// grid layout: [0,64) w1d partials | [64,192) fc2 rowsums | [192, 192+25600) drive
#define NW1D   64
#define NRSUM  128
#define NDRV   (B * T / 4)               // one wave per (b,t) row, 4 waves/block
#define NTOT   (NW1D + NRSUM + NDRV)     // 25792

typedef float v4f __attribute__((ext_vector_type(4)));

// ---------------------------------------------------------------------------
// ws layout (floats):
//   [0, 16384)             w1d partials (16 h-chunks x 1024 b)
//   [16384, 16896)         rowsum_fc2[o]
//   [16896, 119296)        drive[t*B+b]
//   [119296]               (u32) fan-in counter  (memset to 0 each launch)
// ---------------------------------------------------------------------------

__device__ __forceinline__ float delay_of(const float* lor, float cdv) {
    float v = fminf(fmaxf(lor[0], 0.0f), 0.999f);
    float g = 1.0f / sqrtf(1.0f - v * v);
    return expf(-g * fabsf(cdv) * v);
}

__global__ __launch_bounds__(256) void k_fused(const float* __restrict__ x,
                                               const float* __restrict__ cd,
                                               const float* __restrict__ fc1_w,
                                               const float* __restrict__ fc1_b,
                                               const float* __restrict__ fc2_w,
                                               const float* __restrict__ fc2_b,
                                               const float* __restrict__ ta,
                                               const float* __restrict__ lor,
                                               const float* __restrict__ ibeta,
                                               const float* __restrict__ hbeta,
                                               const float* __restrict__ ithr,
                                               const float* __restrict__ hthr,
                                               float* __restrict__ drive,
                                               float* __restrict__ partial,
                                               float* __restrict__ rowsum,
                                               unsigned* __restrict__ counter,
                                               float* __restrict__ out) {
    __shared__ union {
        float dly[IN];                   // drive phase
        float cbuf[16][256];             // finisher phase (16 KB)
    } u;
    __shared__ float S[T], ta_l[T], red[4], sc[4];
    __shared__ unsigned last;

    int blk = blockIdx.x;
    int tid = threadIdx.x;

    if (blk < NW1D) {
        // ---- w1d partials: hc = blk>>2 (h-chunk of 64), bb = blk&3 ----
        int hc = blk >> 2, bb = blk & 3;
        int h0 = hc * 64;
        if (tid < 64) u.dly[tid] = delay_of(lor, cd[h0 + tid]);
        __syncthreads();
        int b = bb * 256 + tid;
        float acc = 0.0f;
        #pragma unroll 8
        for (int k = 0; k < 64; ++k)
            acc += fc1_w[(size_t)(h0 + k) * IN + b] * u.dly[k];
        partial[hc * IN + b] = acc;
    } else if (blk < NW1D + NRSUM) {
        // ---- fc2 rowsums: one wave per output row ----
        int gw = ((blk - NW1D) * 256 + tid) >> 6;            // 512 waves -> OUT rows
        int lane = tid & 63;
        const float4* r = (const float4*)(fc2_w + (size_t)gw * HID);
        float acc = 0.0f;
        #pragma unroll
        for (int k = 0; k < 4; ++k) {
            float4 v = r[k * 64 + lane];
            acc += v.x + v.y + v.z + v.w;
        }
        #pragma unroll
        for (int off = 32; off; off >>= 1) acc += __shfl_xor(acc, off);
        if (lane == 0) rowsum[gw] = acc;
    } else {
        // ---- drive: one wave per (b,t) row, nontemporal x reads ----
        #pragma unroll
        for (int k = 0; k < 4; ++k) {
            int i = k * 256 + tid;
            u.dly[i] = delay_of(lor, cd[i]);
        }
        __syncthreads();
        int gwave = (blk - NW1D - NRSUM) * 4 + (tid >> 6);
        int lane = tid & 63;
        const v4f* xr = (const v4f*)(x + (size_t)gwave * IN);
        const v4f* dl = (const v4f*)u.dly;
        float acc = 0.0f;
        #pragma unroll
        for (int k = 0; k < 4; ++k) {
            int idx = k * 64 + lane;
            v4f xv = __builtin_nontemporal_load(xr + idx);
            v4f dv = dl[idx];
            acc += xv.x * dv.x + xv.y * dv.y + xv.z * dv.z + xv.w * dv.w;
        }
        #pragma unroll
        for (int off = 32; off; off >>= 1) acc += __shfl_xor(acc, off);
        if (lane == 0) {
            int b = gwave / T;
            int t = gwave - b * T;
            drive[t * B + b] = acc;
        }
    }

    // ---- fan-in: last block to finish runs the scan ----
    __threadfence();                      // release our stores device-wide
    __syncthreads();                      // (also guards LDS reuse below)
    if (tid == 0) {
        unsigned old = atomicAdd(counter, 1u);
        last = (old == NTOT - 1) ? 1u : 0u;
    }
    __syncthreads();
    if (!last) return;
    __threadfence();                      // acquire: see all blocks' stores

    // ================= finisher: 256 threads =================
    int wave = tid >> 6, lane = tid & 63;
    if (tid < T) ta_l[tid] = ta[tid];

    // c1 = sum_h fc1_b[h]*delay[h]
    float c = 0.0f;
    #pragma unroll
    for (int j = 0; j < 4; ++j) {
        int h = tid + 256 * j;
        c += fc1_b[h] * delay_of(lor, cd[h]);
    }
    #pragma unroll
    for (int off = 32; off; off >>= 1) c += __shfl_xor(c, off);
    if (lane == 0) red[wave] = c;
    __syncthreads();
    if (tid == 0) sc[0] = red[0] + red[1] + red[2] + red[3];

    // w1d for this thread's 4 b's
    float w[4];
    #pragma unroll
    for (int j = 0; j < 4; ++j) {
        int b = tid + 256 * j;
        float acc = 0.0f;
        #pragma unroll
        for (int cc = 0; cc < 16; ++cc) acc += partial[cc * IN + b];
        w[j] = acc;
    }

    float ib = ibeta[0], it = ithr[0];
    float im[4] = {0.0f, 0.0f, 0.0f, 0.0f};

    for (int t0 = 0; t0 < 96; t0 += 16) {
        #pragma unroll
        for (int tt = 0; tt < 16; ++tt) {
            float ps = 0.0f;
            #pragma unroll
            for (int j = 0; j < 4; ++j) {
                int b = tid + 256 * j;
                im[j] = im[j] * ib + drive[(t0 + tt) * B + b];
                float isp = (im[j] > it) ? 1.0f : 0.0f;
                im[j] *= (1.0f - isp);
                ps += isp * w[j];
            }
            u.cbuf[tt][tid] = ps;
        }
        __syncthreads();
        #pragma unroll
        for (int r = 0; r < 4; ++r) {
            int row = wave * 4 + r;
            float s = 0.0f;
            #pragma unroll
            for (int k = 0; k < 4; ++k) s += u.cbuf[row][lane + 64 * k];
            #pragma unroll
            for (int off = 32; off; off >>= 1) s += __shfl_xor(s, off);
            if (lane == 0) S[t0 + row] = s + sc[0];
        }
        __syncthreads();
    }
    {   // tail: t = 96..99
        #pragma unroll
        for (int tt = 0; tt < 4; ++tt) {
            float ps = 0.0f;
            #pragma unroll
            for (int j = 0; j < 4; ++j) {
                int b = tid + 256 * j;
                im[j] = im[j] * ib + drive[(96 + tt) * B + b];
                float isp = (im[j] > it) ? 1.0f : 0.0f;
                im[j] *= (1.0f - isp);
                ps += isp * w[j];
            }
            u.cbuf[tt][tid] = ps;
        }
        __syncthreads();
        {
            int row = wave;                       // waves 0..3 -> t 96..99
            float s = 0.0f;
            #pragma unroll
            for (int k = 0; k < 4; ++k) s += u.cbuf[row][lane + 64 * k];
            #pragma unroll
            for (int off = 32; off; off >>= 1) s += __shfl_xor(s, off);
            if (lane == 0) S[96 + row] = s + sc[0];
        }
        __syncthreads();
    }

    if (tid == 0) {
        float hb = hbeta[0], ht = hthr[0];
        float hm = 0.0f, wsum = 0.0f, tasum = 0.0f;
        for (int t = 0; t < T; ++t) {
            hm = hm * hb + S[t];
            float hsp = (hm > ht) ? 1.0f : 0.0f;
            hm *= (1.0f - hsp);
            wsum += ta_l[t] * hsp;
            tasum += ta_l[t];
        }
        sc[1] = wsum; sc[2] = tasum;
    }
    __syncthreads();
    #pragma unroll
    for (int j = 0; j < 2; ++j) {
        int o = tid + 256 * j;
        out[o] = sc[1] * rowsum[o] + sc[2] * fc2_b[o];
    }
}

extern "C" void kernel_launch(void* const* d_in, const int* in_sizes, int n_in,
                              void* d_out, int out_size, void* d_ws, size_t ws_size,
                              hipStream_t stream) {
    const float* x      = (const float*)d_in[0];
    const float* cd     = (const float*)d_in[1];
    const float* fc1_w  = (const float*)d_in[2];
    const float* fc1_b  = (const float*)d_in[3];
    const float* fc2_w  = (const float*)d_in[4];
    const float* fc2_b  = (const float*)d_in[5];
    const float* ta     = (const float*)d_in[6];
    const float* lor    = (const float*)d_in[7];
    const float* ibeta  = (const float*)d_in[8];
    const float* hbeta  = (const float*)d_in[9];
    const float* ithr   = (const float*)d_in[10];
    const float* hthr   = (const float*)d_in[11];
    float* out = (float*)d_out;

    float* wsf        = (float*)d_ws;
    float* partial    = wsf;
    float* rowsum     = wsf + 16384;
    float* drive      = wsf + 16896;
    unsigned* counter = (unsigned*)(wsf + 16896 + B * T);

    hipMemsetAsync(counter, 0, sizeof(unsigned), stream);
    k_fused<<<NTOT, 256, 0, stream>>>(x, cd, fc1_w, fc1_b, fc2_w, fc2_b, ta, lor,
                                      ibeta, hbeta, ithr, hthr,
                                      drive, partial, rowsum, counter, out);
}

// Round 6
// 80.357 us; speedup vs baseline: 41.4009x; 41.4009x over previous
//
#include <hip/hip_runtime.h>
#include <math.h>

#define B   1024
#define IN  1024
#define HID 1024
#define OUT 512
#define T   100

// grid split for k_main
#define NDRV (B * T / 4)        // 25600 blocks, one wave per (b,t) row
#define NW1D 64                 // w1d partial blocks
#define NRSUM 128               // fc2 rowsum blocks

typedef float v4f __attribute__((ext_vector_type(4)));

// ---------------------------------------------------------------------------
// ws layout (floats):
//   [0, 16384)            w1d partials (16 h-chunks x 1024 b)
//   [16384, 16896)        rowsum_fc2[o]
//   [16896, 16896+T*B)    drive[t*B+b]
// ---------------------------------------------------------------------------

__device__ __forceinline__ float delay_of(const float* lor, float cdv) {
    float v = fminf(fmaxf(lor[0], 0.0f), 0.999f);
    float g = 1.0f / sqrtf(1.0f - v * v);
    return expf(-g * fabsf(cdv) * v);
}

// blocks [0, NDRV): drive — one wave per (b,t) row, nontemporal x reads
// blocks [NDRV, NDRV+NW1D): w1d partials (hc = q>>2 h-chunk of 64, bb = q&3)
// blocks [NDRV+NW1D, NDRV+NW1D+NRSUM): fc2 rowsums (one wave per output row)
__global__ __launch_bounds__(256) void k_main(const float* __restrict__ x,
                                              const float* __restrict__ cd,
                                              const float* __restrict__ fc1_w,
                                              const float* __restrict__ fc2_w,
                                              const float* __restrict__ lor,
                                              float* __restrict__ drive,
                                              float* __restrict__ partial,
                                              float* __restrict__ rowsum) {
    int blk = blockIdx.x;
    if (blk < NDRV) {
        __shared__ float dly[IN];
        #pragma unroll
        for (int k = 0; k < 4; ++k) {
            int i = k * 256 + threadIdx.x;
            dly[i] = delay_of(lor, cd[i]);
        }
        __syncthreads();
        int gwave = (int)(((size_t)blk * 256 + threadIdx.x) >> 6);
        int lane = threadIdx.x & 63;
        const v4f* xr = (const v4f*)(x + (size_t)gwave * IN);
        const v4f* dl = (const v4f*)dly;
        float acc = 0.0f;
        #pragma unroll
        for (int k = 0; k < 4; ++k) {
            int idx = k * 64 + lane;                       // 16B/lane, coalesced
            v4f xv = __builtin_nontemporal_load(xr + idx); // nt: bypass cache alloc
            v4f dv = dl[idx];
            acc += xv.x * dv.x + xv.y * dv.y + xv.z * dv.z + xv.w * dv.w;
        }
        #pragma unroll
        for (int off = 32; off; off >>= 1) acc += __shfl_xor(acc, off);
        if (lane == 0) {
            int b = gwave / T;
            int t = gwave - b * T;
            drive[t * B + b] = acc;
        }
    } else if (blk < NDRV + NW1D) {
        __shared__ float dly[64];
        int q = blk - NDRV;
        int hc = q >> 2, bb = q & 3;
        int h0 = hc * 64;
        if (threadIdx.x < 64)
            dly[threadIdx.x] = delay_of(lor, cd[h0 + threadIdx.x]);
        __syncthreads();
        int b = bb * 256 + threadIdx.x;
        float acc = 0.0f;
        #pragma unroll 8
        for (int k = 0; k < 64; ++k)
            acc += fc1_w[(size_t)(h0 + k) * IN + b] * dly[k];
        partial[hc * IN + b] = acc;
    } else {
        int gw = ((blk - NDRV - NW1D) * 256 + threadIdx.x) >> 6; // 512 waves -> OUT rows
        int lane = threadIdx.x & 63;
        const float4* r = (const float4*)(fc2_w + (size_t)gw * HID);
        float acc = 0.0f;
        #pragma unroll
        for (int k = 0; k < 4; ++k) {
            float4 v = r[k * 64 + lane];
            acc += v.x + v.y + v.z + v.w;
        }
        #pragma unroll
        for (int off = 32; off; off >>= 1) acc += __shfl_xor(acc, off);
        if (lane == 0) rowsum[gw] = acc;
    }
}

// single block, 1024 threads: c1 + w1d combine + chunked LIF scan + hm scan + output
__global__ __launch_bounds__(1024) void k_scan(const float* __restrict__ drive,
                                               const float* __restrict__ partial,
                                               const float* __restrict__ cd,
                                               const float* __restrict__ fc1_b,
                                               const float* __restrict__ fc2_b,
                                               const float* __restrict__ ta,
                                               const float* __restrict__ lor,
                                               const float* __restrict__ ibeta,
                                               const float* __restrict__ hbeta,
                                               const float* __restrict__ ithr,
                                               const float* __restrict__ hthr,
                                               const float* __restrict__ rowsum,
                                               float* __restrict__ out) {
    __shared__ float cbuf[16][B];   // 64 KB
    __shared__ float red[16];
    __shared__ float S[T];
    __shared__ float ta_l[T];
    __shared__ float sc[4];         // [0]=c1, [1]=wsum, [2]=tasum
    int b = threadIdx.x, wave = b >> 6, lane = b & 63;

    if (b < T) ta_l[b] = ta[b];

    float d = delay_of(lor, cd[b]);
    float c = fc1_b[b] * d;
    #pragma unroll
    for (int off = 32; off; off >>= 1) c += __shfl_xor(c, off);
    if (lane == 0) red[wave] = c;
    __syncthreads();
    if (b == 0) {
        float s = 0.0f;
        #pragma unroll
        for (int k = 0; k < 16; ++k) s += red[k];
        sc[0] = s;
    }

    float w = 0.0f;
    #pragma unroll
    for (int cc = 0; cc < 16; ++cc) w += partial[cc * IN + b];

    float ib = ibeta[0], it = ithr[0];
    float im = 0.0f;

    for (int t0 = 0; t0 < 96; t0 += 16) {
        #pragma unroll
        for (int tt = 0; tt < 16; ++tt) {
            im = im * ib + drive[(t0 + tt) * B + b];
            float isp = (im > it) ? 1.0f : 0.0f;
            im *= (1.0f - isp);
            cbuf[tt][b] = isp * w;
        }
        __syncthreads();
        {
            float s = 0.0f;
            #pragma unroll
            for (int k = 0; k < 16; ++k) s += cbuf[wave][lane + 64 * k];
            #pragma unroll
            for (int off = 32; off; off >>= 1) s += __shfl_xor(s, off);
            if (lane == 0) S[t0 + wave] = s + sc[0];
        }
        __syncthreads();
    }
    {
        #pragma unroll
        for (int tt = 0; tt < 4; ++tt) {
            im = im * ib + drive[(96 + tt) * B + b];
            float isp = (im > it) ? 1.0f : 0.0f;
            im *= (1.0f - isp);
            cbuf[tt][b] = isp * w;
        }
        __syncthreads();
        if (wave < 4) {
            float s = 0.0f;
            #pragma unroll
            for (int k = 0; k < 16; ++k) s += cbuf[wave][lane + 64 * k];
            #pragma unroll
            for (int off = 32; off; off >>= 1) s += __shfl_xor(s, off);
            if (lane == 0) S[96 + wave] = s + sc[0];
        }
        __syncthreads();
    }

    if (b == 0) {
        float hb = hbeta[0], ht = hthr[0];
        float hm = 0.0f, wsum = 0.0f, tasum = 0.0f;
        for (int t = 0; t < T; ++t) {
            hm = hm * hb + S[t];
            float hsp = (hm > ht) ? 1.0f : 0.0f;
            hm *= (1.0f - hsp);
            wsum += ta_l[t] * hsp;
            tasum += ta_l[t];
        }
        sc[1] = wsum; sc[2] = tasum;
    }
    __syncthreads();
    if (b < OUT) out[b] = sc[1] * rowsum[b] + sc[2] * fc2_b[b];
}

extern "C" void kernel_launch(void* const* d_in, const int* in_sizes, int n_in,
                              void* d_out, int out_size, void* d_ws, size_t ws_size,
                              hipStream_t stream) {
    const float* x      = (const float*)d_in[0];
    const float* cd     = (const float*)d_in[1];
    const float* fc1_w  = (const float*)d_in[2];
    const float* fc1_b  = (const float*)d_in[3];
    const float* fc2_w  = (const float*)d_in[4];
    const float* fc2_b  = (const float*)d_in[5];
    const float* ta     = (const float*)d_in[6];
    const float* lor    = (const float*)d_in[7];
    const float* ibeta  = (const float*)d_in[8];
    const float* hbeta  = (const float*)d_in[9];
    const float* ithr   = (const float*)d_in[10];
    const float* hthr   = (const float*)d_in[11];
    float* out = (float*)d_out;

    float* wsf     = (float*)d_ws;
    float* partial = wsf;
    float* rowsum  = wsf + 16384;
    float* drive   = wsf + 16896;

    k_main<<<NDRV + NW1D + NRSUM, 256, 0, stream>>>(x, cd, fc1_w, fc2_w, lor,
                                                    drive, partial, rowsum);
    k_scan<<<1, 1024, 0, stream>>>(drive, partial, cd, fc1_b, fc2_b, ta, lor,
                                   ibeta, hbeta, ithr, hthr, rowsum, out);
}